// Round 3
// baseline (104068.030 us; speedup 1.0000x reference)
//
#include <hip/hip_runtime.h>
#include <math.h>

// Problem constants
#define BB   64
#define SS   512
#define EE   256
#define HH   512
#define HD   1024
#define TT   9
#define MM   (BB*SS)      // 32768 rows

// bf16 helpers (storage only; math stays fp32)
__device__ __forceinline__ float bfu2f(unsigned short u) {
    return __uint_as_float(((unsigned)u) << 16);
}
__device__ __forceinline__ unsigned short f2bfu(float x) {
    unsigned b = __float_as_uint(x);
    b += 0x7FFFu + ((b >> 16) & 1u);      // RNE
    return (unsigned short)(b >> 16);
}

// ---------------------------------------------------------------------------
// Grid-stride zero-fill (graph-safe)
// ---------------------------------------------------------------------------
__global__ void zero_kernel(float* __restrict__ p, int n)
{
    int i = blockIdx.x * blockDim.x + threadIdx.x;
    int stride = gridDim.x * blockDim.x;
    for (; i < n; i += stride) p[i] = 0.f;
}

// ---------------------------------------------------------------------------
// Persistent BiLSTM layer kernel. ONE launch runs all 512 timesteps.
// Grid: 256 blocks x 256 threads, all co-resident (46KB LDS -> >=1 block/CU).
//   block: d = blockIdx>>7 (direction), j0 = (blockIdx&127)*4 (4 hidden units)
//   thread: wave ks = tid>>6 owns K-quarter; lane = (bt 0..15, rt 0..3);
//           computes acc[4 gates][4 batches], batches b = bt + 16*bb.
// Fused input projection (x @ w_ih^T): K-chunks cover [x: KX | h: 512].
// Each wave stages its own chunks into private LDS quarters -> NO
// __syncthreads in the K loop. End of step: cross-wave reduction in LDS,
// wave 0 does gates/c/h epilogue (c lives in wave-0 registers all 512 steps).
// Cross-block dependency (h_prev) via per-dir barrier: h published with
// agent-scope stores, re-read with agent-scope loads (bypasses stale L1/L2
// without invalidating the caches that hold the streamed weights).
// ---------------------------------------------------------------------------
template<int LAYER>
__global__ __launch_bounds__(256)
void bilstm_persist(const int* __restrict__ ids, const float* __restrict__ emb,
                    const unsigned short* __restrict__ x1,   // layer1 x = h0out (bf16)
                    const float* __restrict__ w_ih, const float* __restrict__ w_hh,
                    const float* __restrict__ b_ih, const float* __restrict__ b_hh,
                    const float* __restrict__ cls_w,
                    float* hping,                 // [2][2][64][512] fp32 ping-pong
                    unsigned short* __restrict__ h0out,   // layer0 output (bf16)
                    float* __restrict__ logits,   // layer1 output (atomic accum)
                    unsigned* cnt)                // 2 counters (this layer)
{
    constexpr int KX  = (LAYER == 0) ? EE : HD;   // x feature dim
    constexpr int NCH = (KX + HH) / 32;           // 32-wide K chunks
    constexpr int CPQ = NCH / 4;                  // chunks per K-quarter (wave)
    constexpr int XCH = KX / 32;                  // x chunks

    __shared__ float Xs[4][64][36];   // per-wave staging quarter [b][k]
    __shared__ float Ws[4][16][36];   // per-wave weight quarter [row][k]
    float* Red = (float*)Xs;          // [4][64][20] reduction scratch (aliased)

    const int bid  = blockIdx.x;
    const int d    = bid >> 7;
    const int j0   = (bid & 127) * 4;
    const int tid  = threadIdx.x;
    const int lane = tid & 63;
    const int ks   = tid >> 6;
    const int bt   = lane & 15;
    const int rt   = lane >> 4;
    const int jme  = j0 + rt;

    float bias_[4];
    #pragma unroll
    for (int q = 0; q < 4; q++)
        bias_[q] = b_ih[d*2048 + q*HH + jme] + b_hh[d*2048 + q*HH + jme];

    float clsw[TT];
    if (LAYER == 1) {
        #pragma unroll
        for (int n = 0; n < TT; n++) clsw[n] = cls_w[n*HD + d*HH + jme];
    }
    float c_[4] = {0.f, 0.f, 0.f, 0.f};

    for (int s = 0; s < SS; s++) {
        const int t = d ? (SS - 1 - s) : s;
        float acc[4][4] = {};   // [gate q][batch bb]

        for (int ci = 0; ci < CPQ; ci++) {
            const int  c   = ks*CPQ + ci;
            const bool isX = (c < XCH);
            if (!isX && s == 0) continue;          // h == 0 at first step
            const int k0 = isX ? c*32 : (c - XCH)*32;

            // ---- stage x/h chunk [64 b][32 k] into this wave's quarter
            if (isX) {
                #pragma unroll
                for (int r = 0; r < 8; r++) {
                    int f4  = lane + r*64;         // 0..511
                    int row = f4 >> 3;
                    int c4  = (f4 & 7) * 4;
                    float4 v;
                    if (LAYER == 0) {
                        v = *(const float4*)(emb + (size_t)ids[row*SS + t]*EE + k0 + c4);
                    } else {
                        ushort4 u = *(const ushort4*)(x1 + ((size_t)(row*SS + t))*HD + k0 + c4);
                        v.x = bfu2f(u.x); v.y = bfu2f(u.y); v.z = bfu2f(u.z); v.w = bfu2f(u.w);
                    }
                    *(float4*)&Xs[ks][row][c4] = v;
                }
            } else {
                float* hsrc = hping + ((size_t)((s&1)*2 + d))*(BB*HH) + k0;
                #pragma unroll
                for (int r = 0; r < 32; r++) {
                    int fid = lane + r*64;         // 0..2047
                    int row = fid >> 5;
                    int cc  = fid & 31;
                    Xs[ks][row][cc] = __hip_atomic_load(hsrc + row*HH + cc,
                                        __ATOMIC_RELAXED, __HIP_MEMORY_SCOPE_AGENT);
                }
            }
            // ---- stage weight chunk [16 rows][32 k]; row rr = q*4 + jj
            const float* wsrc = isX ? (w_ih + (size_t)d*2048*KX)
                                    : (w_hh + (size_t)d*2048*HH);
            const int wld = isX ? KX : HH;
            #pragma unroll
            for (int r = 0; r < 2; r++) {
                int f4 = lane + r*64;              // 0..127
                int rr = f4 >> 3;                  // 0..15
                int c4 = (f4 & 7) * 4;
                int q = rr >> 2, jj = rr & 3;
                *(float4*)&Ws[ks][rr][c4] =
                    *(const float4*)(wsrc + (size_t)(q*HH + j0 + jj)*wld + k0 + c4);
            }
            // ---- inner: 8 groups of 4 k; 8 LDS b128 reads feed 64 FMAs
            #pragma unroll
            for (int g = 0; g < 8; g++) {
                float4 wv[4], hv[4];
                #pragma unroll
                for (int q = 0; q < 4; q++)  wv[q]  = *(const float4*)&Ws[ks][q*4 + rt][g*4];
                #pragma unroll
                for (int bb = 0; bb < 4; bb++) hv[bb] = *(const float4*)&Xs[ks][bt + 16*bb][g*4];
                #pragma unroll
                for (int q = 0; q < 4; q++)
                    #pragma unroll
                    for (int bb = 0; bb < 4; bb++)
                        acc[q][bb] += hv[bb].x*wv[q].x + hv[bb].y*wv[q].y
                                    + hv[bb].z*wv[q].z + hv[bb].w*wv[q].w;
            }
        }

        // ---- cross-wave K reduction
        __syncthreads();                           // everyone done with Xs
        #pragma unroll
        for (int q = 0; q < 4; q++)
            #pragma unroll
            for (int bb = 0; bb < 4; bb++)
                Red[(ks*64 + lane)*20 + q*4 + bb] = acc[q][bb];
        __syncthreads();

        if (ks == 0) {                             // wave 0: epilogue, owns c
            float* hw = hping + ((size_t)(((s+1)&1)*2 + d))*(BB*HH);
            #pragma unroll
            for (int bb = 0; bb < 4; bb++) {
                float gv[4];
                #pragma unroll
                for (int q = 0; q < 4; q++) {
                    float sum = bias_[q];
                    #pragma unroll
                    for (int kk = 0; kk < 4; kk++)
                        sum += Red[(kk*64 + lane)*20 + q*4 + bb];
                    gv[q] = sum;
                }
                float i_ = 1.f / (1.f + expf(-gv[0]));
                float f_ = 1.f / (1.f + expf(-gv[1]));
                float g_ = tanhf(gv[2]);
                float o_ = 1.f / (1.f + expf(-gv[3]));
                c_[bb] = f_ * c_[bb] + i_ * g_;
                float hn = o_ * tanhf(c_[bb]);
                const int b = bt + 16*bb;
                __hip_atomic_store(hw + b*HH + jme, hn,
                                   __ATOMIC_RELAXED, __HIP_MEMORY_SCOPE_AGENT);
                if (LAYER == 0) {
                    h0out[((size_t)(b*SS + t))*HD + d*HH + jme] = f2bfu(hn);
                } else {
                    #pragma unroll
                    for (int n = 0; n < TT; n++) {
                        float v = hn * clsw[n];
                        v += __shfl_xor(v, 16);    // reduce over rt (4 j's)
                        v += __shfl_xor(v, 32);
                        if (rt == 0)
                            atomicAdd(&logits[((size_t)(b*SS + t))*TT + n], v);
                    }
                }
            }
        }

        // ---- per-direction grid barrier (128 blocks)
        if (s < SS - 1) {
            if (tid == 0) {
                unsigned tgt = 128u * (unsigned)(s + 1);
                __hip_atomic_fetch_add(&cnt[d], 1u, __ATOMIC_RELEASE,
                                       __HIP_MEMORY_SCOPE_AGENT);
                while (__hip_atomic_load(&cnt[d], __ATOMIC_ACQUIRE,
                                         __HIP_MEMORY_SCOPE_AGENT) < tgt)
                    __builtin_amdgcn_s_sleep(8);
            }
            __syncthreads();
        }
    }
}

// ---------------------------------------------------------------------------
// CRF viterbi decode + loss per batch row. 1 wave per row. cls_b folded in.
// (validated round 2)
// ---------------------------------------------------------------------------
__global__ __launch_bounds__(64)
void crf_kernel(const float* __restrict__ logits, const int* __restrict__ labels,
                const int* __restrict__ vlens, const float* __restrict__ trans,
                const float* __restrict__ start_t, const float* __restrict__ end_t,
                const float* __restrict__ cls_b,
                float* __restrict__ tags_out, float* __restrict__ llh)
{
    const int b = blockIdx.x;
    const int lane = threadIdx.x;
    const int len = vlens[b];
    const float* em = logits + (size_t)b * (SS*TT);
    const int*  lab = labels + (size_t)b * SS;
    __shared__ unsigned char hist[(SS-1)*TT];

    float cb = (lane < TT) ? cls_b[lane] : 0.f;
    float tcol[TT];
    #pragma unroll
    for (int i = 0; i < TT; i++) tcol[i] = (lane < TT) ? trans[i*TT + lane] : 0.f;
    float score = (lane < TT) ? (start_t[lane] + em[lane] + cb) : 0.f;
    float alpha = score;
    float num = 0.f; int plab = 0;
    if (lane == 0) { plab = lab[0]; num = start_t[plab] + em[plab] + cls_b[plab]; }

    for (int t = 1; t < SS; t++) {
        float emj = (lane < TT) ? (em[t*TT + lane] + cb) : 0.f;
        float sv[TT], av[TT];
        #pragma unroll
        for (int i = 0; i < TT; i++) { sv[i] = __shfl(score, i); av[i] = __shfl(alpha, i); }
        float best = -INFINITY; int bp = 0; float amx = -INFINITY;
        #pragma unroll
        for (int i = 0; i < TT; i++) {
            float cnd = sv[i] + tcol[i];
            if (cnd > best) { best = cnd; bp = i; }   // strict >: FIRST max (jnp.argmax)
            amx = fmaxf(amx, av[i] + tcol[i]);
        }
        float se = 0.f;
        #pragma unroll
        for (int i = 0; i < TT; i++) se += expf(av[i] + tcol[i] - amx);
        const bool m = (t < len);
        if (m) { score = best + emj; alpha = amx + logf(se) + emj; }
        if (lane < TT) hist[(t-1)*TT + lane] = (unsigned char)bp;
        if (lane == 0 && m) {
            int lt = lab[t];
            num += em[t*TT + lt] + cls_b[lt] + trans[plab*TT + lt];
            plab = lt;
        }
    }
    float fsc[TT], fal[TT];
    #pragma unroll
    for (int i = 0; i < TT; i++) { fsc[i] = __shfl(score, i); fal[i] = __shfl(alpha, i); }
    __syncthreads();
    if (lane == 0) {
        num += end_t[lab[len-1]];
        int bl = 0; float bv = fsc[0] + end_t[0];
        #pragma unroll
        for (int i = 1; i < TT; i++) {
            float v = fsc[i] + end_t[i];
            if (v > bv) { bv = v; bl = i; }
        }
        float zmx = -INFINITY;
        #pragma unroll
        for (int i = 0; i < TT; i++) zmx = fmaxf(zmx, fal[i] + end_t[i]);
        float zse = 0.f;
        #pragma unroll
        for (int i = 0; i < TT; i++) zse += expf(fal[i] + end_t[i] - zmx);
        llh[b] = num - (zmx + logf(zse));
        int tag = bl;
        tags_out[b*SS + (SS-1)] = (float)tag;
        for (int t = SS-2; t >= 0; t--) {
            if (t + 1 < len) tag = hist[t*TT + tag];
            tags_out[b*SS + t] = (float)tag;
        }
    }
}

__global__ void loss_kernel(const float* __restrict__ llh, float* __restrict__ out)
{
    float v = llh[threadIdx.x];
    #pragma unroll
    for (int off = 32; off > 0; off >>= 1) v += __shfl_down(v, off);
    if (threadIdx.x == 0) out[MM] = -(v / 64.f);
}

// ---------------------------------------------------------------------------
extern "C" void kernel_launch(void* const* d_in, const int* in_sizes, int n_in,
                              void* d_out, int out_size, void* d_ws, size_t ws_size,
                              hipStream_t stream)
{
    const int*   ids     = (const int*)  d_in[0];
    const int*   vlen    = (const int*)  d_in[1];
    const int*   labels  = (const int*)  d_in[2];
    const float* emb     = (const float*)d_in[3];
    const float* w_ih0   = (const float*)d_in[4];
    const float* w_hh0   = (const float*)d_in[5];
    const float* b_ih0   = (const float*)d_in[6];
    const float* b_hh0   = (const float*)d_in[7];
    const float* w_ih1   = (const float*)d_in[8];
    const float* w_hh1   = (const float*)d_in[9];
    const float* b_ih1   = (const float*)d_in[10];
    const float* b_hh1   = (const float*)d_in[11];
    const float* cls_w   = (const float*)d_in[12];
    const float* cls_b   = (const float*)d_in[13];
    const float* trans   = (const float*)d_in[14];
    const float* start_t = (const float*)d_in[15];
    const float* end_t   = (const float*)d_in[16];

    // Workspace (~69 MB):
    //  [logits MM*9 f32][cnt 4 u32][llh 64 f32][hping 2*2*64*512 f32][h0out MM*1024 bf16]
    float*          ws     = (float*)d_ws;
    float*          logits = ws;
    unsigned*       cnt    = (unsigned*)(logits + (size_t)MM*TT);
    float*          llh    = (float*)(cnt + 4);
    float*          hping  = llh + 64;
    unsigned short* h0out  = (unsigned short*)(hping + 2*2*BB*HH);

    // zero logits + barrier counters (counters MUST be re-zeroed every call)
    zero_kernel<<<512, 256, 0, stream>>>(logits, MM*TT + 4);

    bilstm_persist<0><<<256, 256, 0, stream>>>(
        ids, emb, nullptr, w_ih0, w_hh0, b_ih0, b_hh0, nullptr,
        hping, h0out, nullptr, cnt);

    bilstm_persist<1><<<256, 256, 0, stream>>>(
        nullptr, nullptr, h0out, w_ih1, w_hh1, b_ih1, b_hh1, cls_w,
        hping, nullptr, logits, cnt + 2);

    crf_kernel<<<BB, 64, 0, stream>>>(logits, labels, vlen, trans, start_t, end_t,
                                      cls_b, (float*)d_out, llh);
    loss_kernel<<<1, 64, 0, stream>>>(llh, (float*)d_out);
}

// Round 4
// 41266.864 us; speedup vs baseline: 2.5218x; 2.5218x over previous
//
#include <hip/hip_runtime.h>
#include <math.h>

// Problem constants
#define BB 64
#define SS 512
#define EE 256
#define HH 512
#define HD 1024
#define TT 9
#define MM (BB*SS)

typedef __attribute__((ext_vector_type(8))) short      short8;   // 8 bf16
typedef __attribute__((ext_vector_type(4))) float      f32x4;
typedef __attribute__((ext_vector_type(4))) unsigned   uint4v;

__device__ __forceinline__ unsigned short f2bfu(float x) {
    unsigned b = __float_as_uint(x);
    b += 0x7FFFu + ((b >> 16) & 1u);      // RNE
    return (unsigned short)(b >> 16);
}
__device__ __forceinline__ unsigned pack2bf(float lo, float hi) {
    return ((unsigned)f2bfu(hi) << 16) | (unsigned)f2bfu(lo);
}

// ---------------------------------------------------------------------------
__global__ void zero_kernel(float* __restrict__ p, int n)
{
    int i = blockIdx.x * blockDim.x + threadIdx.x;
    int stride = gridDim.x * blockDim.x;
    for (; i < n; i += stride) p[i] = 0.f;
}

// ---------------------------------------------------------------------------
// Pack [w_ih | w_hh] (fp32) into MFMA-A-fragment-linear bf16:
// dst[tid], tid = ((((d*16+jb)*nch + ch)*16 + fr)*64 + lane)*8 + j
// fr = ksl*8 + mt; A-element: row r = mt*16 + (lane&15) -> gate q=r>>5, jj=r&31
// packed k = ch*64 + ksl*32 + (lane>>4)*8 + j;  k<KX -> w_ih else w_hh.
// ---------------------------------------------------------------------------
__global__ void pack_kernel(const float* __restrict__ w_ih, const float* __restrict__ w_hh,
                            unsigned short* __restrict__ dst, int KX, int nch, int total)
{
    int tid = blockIdx.x * 256 + threadIdx.x;
    if (tid >= total) return;
    int u = tid;
    int j    = u & 7;  u >>= 3;
    int lane = u & 63; u >>= 6;
    int fr   = u & 15; u >>= 4;
    int ch   = u % nch; u /= nch;
    int jb   = u & 15; u >>= 4;
    int d    = u;
    int ksl = fr >> 3, mt = fr & 7;
    int quad = lane >> 4, m = lane & 15;
    int r = mt * 16 + m;
    int q = r >> 5, jj = r & 31;
    int row = q * HH + jb * 32 + jj;
    int kp  = ch * 64 + ksl * 32 + quad * 8 + j;
    float v;
    if (kp < KX) v = w_ih[((size_t)d * 2048 + row) * (size_t)KX + kp];
    else         v = w_hh[((size_t)d * 2048 + row) * (size_t)HH + (kp - KX)];
    dst[tid] = f2bfu(v);
}

// ---------------------------------------------------------------------------
// Persistent BiLSTM layer. 32 blocks x 128 threads (2 waves), all resident.
//   bid>>4 = dir d, bid&15 = jb (32 hidden units). Wave wv owns batch tiles
//   {2wv, 2wv+1} (n-split). Gates via mfma_f32_16x16x32_bf16, fp32 accum.
// K-chunks (64 wide): [x: KX/64 chunks][h: 8 chunks]. x-chunks run BEFORE the
// 16-block per-dir barrier wait -> sync latency hidden. A double-buffered in
// frag-linear LDS (conflict-free b128). B prefetched 1 chunk ahead in regs.
// h exchange: bf16 global, agent-scope (publish stores drained by the
// pre-barrier syncthreads; release fetch_add; acquire spin) — round-3-validated.
// ---------------------------------------------------------------------------
template<int LAYER>
__global__ __launch_bounds__(128, 1)
void bilstm_persist(const int* __restrict__ ids, const float* __restrict__ emb,
                    const unsigned short* __restrict__ x1,
                    const unsigned short* __restrict__ packA,
                    const float* __restrict__ b_ih, const float* __restrict__ b_hh,
                    const float* __restrict__ cls_w,
                    unsigned short* hbuf,                // [2 dir][2 ping][64][512] bf16
                    unsigned short* __restrict__ h0out,  // layer0 out (bf16)
                    float* __restrict__ plog,            // [32][64][512][9]
                    unsigned* cnt)
{
    constexpr int KX  = LAYER ? HD : EE;
    constexpr int NCH = (KX + HH) / 64;
    constexpr int XCH = KX / 64;

    __shared__ uint4v Abuf[2][1024];    // 2 x 16 KB, frag-linear

    const int bid  = blockIdx.x;
    const int d    = bid >> 4;
    const int jb   = bid & 15;
    const int tid  = threadIdx.x;
    const int lane = tid & 63;
    const int wv   = tid >> 6;
    const int quad = lane >> 4;
    const int ln15 = lane & 15;
    const int b0   = (wv * 2 + 0) * 16 + ln15;
    const int b1   = (wv * 2 + 1) * 16 + ln15;

    const unsigned short* myA = packA + (size_t)((d * 16 + jb) * NCH) * 8192;

    float bias_[4][2][4];
    #pragma unroll
    for (int q = 0; q < 4; q++)
        #pragma unroll
        for (int hi = 0; hi < 2; hi++)
            #pragma unroll
            for (int i = 0; i < 4; i++) {
                int jj  = hi * 16 + quad * 4 + i;
                int row = d * 2048 + q * HH + jb * 32 + jj;
                bias_[q][hi][i] = b_ih[row] + b_hh[row];
            }

    float clsw[8][TT];
    if (LAYER == 1) {
        #pragma unroll
        for (int hi = 0; hi < 2; hi++)
            #pragma unroll
            for (int i = 0; i < 4; i++) {
                int jj = hi * 16 + quad * 4 + i;
                #pragma unroll
                for (int n = 0; n < TT; n++)
                    clsw[hi * 4 + i][n] = cls_w[n * HD + d * HH + jb * 32 + jj];
            }
    }

    auto stageA = [&](int ch, int bb) {
        const uint4v* src = (const uint4v*)(myA + (size_t)ch * 8192);
        #pragma unroll
        for (int r = 0; r < 8; r++)
            Abuf[bb][tid + r * 128] = src[tid + r * 128];
    };

    // B-fragment: lane holds B[k=quad*8+j][n] = src[n][k0+quad*8+j] (8 bf16)
    auto loadB = [&](int ch, int t, int p, int ksl, int b) -> uint4v {
        int k0 = ch * 64 + ksl * 32 + quad * 8;
        uint4v u;
        if (ch < XCH) {
            if (LAYER == 0) {
                int id = ids[b * SS + t];
                const float* er = emb + (size_t)id * EE + k0;
                float4 f0 = *(const float4*)(er);
                float4 f1 = *(const float4*)(er + 4);
                u[0] = pack2bf(f0.x, f0.y);
                u[1] = pack2bf(f0.z, f0.w);
                u[2] = pack2bf(f1.x, f1.y);
                u[3] = pack2bf(f1.z, f1.w);
            } else {
                u = *(const uint4v*)(x1 + ((size_t)(b * SS + t)) * HD + k0);
            }
        } else {
            int kh = (ch - XCH) * 64 + ksl * 32 + quad * 8;
            const unsigned long long* hp = (const unsigned long long*)
                (hbuf + ((size_t)((d * 2 + p) * BB + b)) * HH + kh);
            unsigned long long l0 = __hip_atomic_load(hp,     __ATOMIC_RELAXED, __HIP_MEMORY_SCOPE_AGENT);
            unsigned long long l1 = __hip_atomic_load(hp + 1, __ATOMIC_RELAXED, __HIP_MEMORY_SCOPE_AGENT);
            u[0] = (unsigned)l0; u[1] = (unsigned)(l0 >> 32);
            u[2] = (unsigned)l1; u[3] = (unsigned)(l1 >> 32);
        }
        return u;
    };

    float  c_[2][2][4] = {};            // [nt-local][hi][i]
    f32x4  acc[8][2];
    uint4v breg[2][2][2];               // [buf][ksl][nt-local]

    // prime: stage chunk 0, prefetch its B (step 0)
    stageA(0, 0);
    {
        int t0 = d ? (SS - 1) : 0;
        #pragma unroll
        for (int ksl = 0; ksl < 2; ksl++) {
            breg[0][ksl][0] = loadB(0, t0, 0, ksl, b0);
            breg[0][ksl][1] = loadB(0, t0, 0, ksl, b1);
        }
    }

    for (int s = 0; s < SS; s++) {
        const int t   = d ? (SS - 1 - s) : s;
        const int tn  = d ? (t - 1) : (t + 1);
        const int tnc = tn < 0 ? 0 : (tn > SS - 1 ? SS - 1 : tn);
        const int p   = s & 1;

        #pragma unroll
        for (int mt = 0; mt < 8; mt++) {
            acc[mt][0] = f32x4{0.f, 0.f, 0.f, 0.f};
            acc[mt][1] = f32x4{0.f, 0.f, 0.f, 0.f};
        }

        for (int ch = 0; ch < NCH; ch++) {
            const int cur = ch & 1, nxt = cur ^ 1;
            __syncthreads();                      // Abuf[cur]/breg[cur] ready; Abuf[nxt] free
            if (ch == XCH - 1) {                  // before first h prefetch
                if (tid == 0) {
                    unsigned tgt = 16u * (unsigned)s;
                    while (__hip_atomic_load(&cnt[d], __ATOMIC_ACQUIRE,
                                             __HIP_MEMORY_SCOPE_AGENT) < tgt)
                        __builtin_amdgcn_s_sleep(1);
                }
                __syncthreads();
            }
            // stage + prefetch next chunk (wraps to next step's chunk 0 = x)
            {
                int ch2 = ch + 1, t2 = t, p2 = p;
                if (ch2 == NCH) { ch2 = 0; t2 = tnc; p2 = p ^ 1; }
                stageA(ch2, nxt);
                #pragma unroll
                for (int ksl = 0; ksl < 2; ksl++) {
                    breg[nxt][ksl][0] = loadB(ch2, t2, p2, ksl, b0);
                    breg[nxt][ksl][1] = loadB(ch2, t2, p2, ksl, b1);
                }
            }
            // MFMA current chunk: 2 ksl x 8 mt x 2 nt
            #pragma unroll
            for (int ksl = 0; ksl < 2; ksl++) {
                short8 bf0 = __builtin_bit_cast(short8, breg[cur][ksl][0]);
                short8 bf1 = __builtin_bit_cast(short8, breg[cur][ksl][1]);
                #pragma unroll
                for (int mt = 0; mt < 8; mt++) {
                    short8 a = __builtin_bit_cast(short8, Abuf[cur][(ksl * 8 + mt) * 64 + lane]);
                    acc[mt][0] = __builtin_amdgcn_mfma_f32_16x16x32_bf16(a, bf0, acc[mt][0], 0, 0, 0);
                    acc[mt][1] = __builtin_amdgcn_mfma_f32_16x16x32_bf16(a, bf1, acc[mt][1], 0, 0, 0);
                }
            }
        }

        // ---- epilogue: lane owns (b in {b0,b1}) x (jj = hi*16+quad*4+i)
        float pl[2][TT];
        if (LAYER == 1) {
            #pragma unroll
            for (int ntl = 0; ntl < 2; ntl++)
                #pragma unroll
                for (int n = 0; n < TT; n++) pl[ntl][n] = 0.f;
        }
        #pragma unroll
        for (int ntl = 0; ntl < 2; ntl++) {
            const int b = ntl ? b1 : b0;
            #pragma unroll
            for (int hi = 0; hi < 2; hi++) {
                #pragma unroll
                for (int i = 0; i < 4; i++) {
                    float gi = acc[0 + hi][ntl][i] + bias_[0][hi][i];
                    float gf = acc[2 + hi][ntl][i] + bias_[1][hi][i];
                    float gg = acc[4 + hi][ntl][i] + bias_[2][hi][i];
                    float go = acc[6 + hi][ntl][i] + bias_[3][hi][i];
                    float i_ = 1.f / (1.f + __expf(-gi));
                    float f_ = 1.f / (1.f + __expf(-gf));
                    float xg = fminf(fmaxf(gg, -15.f), 15.f);
                    float e2 = __expf(2.f * xg);
                    float g_ = (e2 - 1.f) / (e2 + 1.f);
                    float o_ = 1.f / (1.f + __expf(-go));
                    float cc = f_ * c_[ntl][hi][i] + i_ * g_;
                    c_[ntl][hi][i] = cc;
                    float xc  = fminf(fmaxf(cc, -15.f), 15.f);
                    float e2c = __expf(2.f * xc);
                    float th  = (e2c - 1.f) / (e2c + 1.f);
                    float hn  = o_ * th;
                    int jj = hi * 16 + quad * 4 + i;
                    __hip_atomic_store(hbuf + ((size_t)((d * 2 + (p ^ 1)) * BB + b)) * HH
                                            + jb * 32 + jj,
                                       f2bfu(hn), __ATOMIC_RELAXED, __HIP_MEMORY_SCOPE_AGENT);
                    if (LAYER == 0) {
                        h0out[((size_t)(b * SS + t)) * HD + d * HH + jb * 32 + jj] = f2bfu(hn);
                    } else {
                        #pragma unroll
                        for (int n = 0; n < TT; n++) pl[ntl][n] += hn * clsw[hi * 4 + i][n];
                    }
                }
            }
        }
        if (LAYER == 1) {
            #pragma unroll
            for (int ntl = 0; ntl < 2; ntl++)
                #pragma unroll
                for (int n = 0; n < TT; n++) {
                    float v = pl[ntl][n];
                    v += __shfl_xor(v, 16);
                    v += __shfl_xor(v, 32);
                    pl[ntl][n] = v;
                }
            if (ln15 == lane) {                   // lanes 0..15 (quad 0)
                #pragma unroll
                for (int ntl = 0; ntl < 2; ntl++) {
                    int b = (wv * 2 + ntl) * 16 + lane;
                    float* dstp = plog + (((size_t)(d * 16 + jb) * BB + b) * SS + t) * TT;
                    #pragma unroll
                    for (int n = 0; n < TT; n++) dstp[n] = pl[ntl][n];
                }
            }
        }
        // arrive: syncthreads drains every wave's vmem (s_waitcnt vmcnt(0)
        // before s_barrier) -> h stores complete before the release add.
        __syncthreads();
        if (tid == 0)
            __hip_atomic_fetch_add(&cnt[d], 1u, __ATOMIC_RELEASE, __HIP_MEMORY_SCOPE_AGENT);
    }
}

// ---------------------------------------------------------------------------
// logits[i] = sum over 32 (dir,jb) partials  (cls_b added in CRF kernel)
// ---------------------------------------------------------------------------
__global__ void reduce_logits(const float* __restrict__ plog, float* __restrict__ out)
{
    int i = blockIdx.x * 256 + threadIdx.x;
    if (i >= MM * TT) return;
    float s = 0.f;
    #pragma unroll
    for (int g = 0; g < 32; g++) s += plog[(size_t)g * (MM * TT / BB) * BB + i];
    out[i] = s;
}

// ---------------------------------------------------------------------------
// CRF viterbi + loss (validated round 2/3). cls_b folded here.
// ---------------------------------------------------------------------------
__global__ __launch_bounds__(64)
void crf_kernel(const float* __restrict__ logits, const int* __restrict__ labels,
                const int* __restrict__ vlens, const float* __restrict__ trans,
                const float* __restrict__ start_t, const float* __restrict__ end_t,
                const float* __restrict__ cls_b,
                float* __restrict__ tags_out, float* __restrict__ llh)
{
    const int b = blockIdx.x;
    const int lane = threadIdx.x;
    const int len = vlens[b];
    const float* em = logits + (size_t)b * (SS * TT);
    const int*  lab = labels + (size_t)b * SS;
    __shared__ unsigned char hist[(SS - 1) * TT];

    float cb = (lane < TT) ? cls_b[lane] : 0.f;
    float tcol[TT];
    #pragma unroll
    for (int i = 0; i < TT; i++) tcol[i] = (lane < TT) ? trans[i * TT + lane] : 0.f;
    float score = (lane < TT) ? (start_t[lane] + em[lane] + cb) : 0.f;
    float alpha = score;
    float num = 0.f; int plab = 0;
    if (lane == 0) { plab = lab[0]; num = start_t[plab] + em[plab] + cls_b[plab]; }

    for (int t = 1; t < SS; t++) {
        float emj = (lane < TT) ? (em[t * TT + lane] + cb) : 0.f;
        float sv[TT], av[TT];
        #pragma unroll
        for (int i = 0; i < TT; i++) { sv[i] = __shfl(score, i); av[i] = __shfl(alpha, i); }
        float best = -INFINITY; int bp = 0; float amx = -INFINITY;
        #pragma unroll
        for (int i = 0; i < TT; i++) {
            float cnd = sv[i] + tcol[i];
            if (cnd > best) { best = cnd; bp = i; }   // strict >: FIRST max
            amx = fmaxf(amx, av[i] + tcol[i]);
        }
        float se = 0.f;
        #pragma unroll
        for (int i = 0; i < TT; i++) se += expf(av[i] + tcol[i] - amx);
        const bool m = (t < len);
        if (m) { score = best + emj; alpha = amx + logf(se) + emj; }
        if (lane < TT) hist[(t - 1) * TT + lane] = (unsigned char)bp;
        if (lane == 0 && m) {
            int lt = lab[t];
            num += em[t * TT + lt] + cls_b[lt] + trans[plab * TT + lt];
            plab = lt;
        }
    }
    float fsc[TT], fal[TT];
    #pragma unroll
    for (int i = 0; i < TT; i++) { fsc[i] = __shfl(score, i); fal[i] = __shfl(alpha, i); }
    __syncthreads();
    if (lane == 0) {
        num += end_t[lab[len - 1]];
        int bl = 0; float bv = fsc[0] + end_t[0];
        #pragma unroll
        for (int i = 1; i < TT; i++) {
            float v = fsc[i] + end_t[i];
            if (v > bv) { bv = v; bl = i; }
        }
        float zmx = -INFINITY;
        #pragma unroll
        for (int i = 0; i < TT; i++) zmx = fmaxf(zmx, fal[i] + end_t[i]);
        float zse = 0.f;
        #pragma unroll
        for (int i = 0; i < TT; i++) zse += expf(fal[i] + end_t[i] - zmx);
        llh[b] = num - (zmx + logf(zse));
        int tag = bl;
        tags_out[b * SS + (SS - 1)] = (float)tag;
        for (int t = SS - 2; t >= 0; t--) {
            if (t + 1 < len) tag = hist[t * TT + tag];
            tags_out[b * SS + t] = (float)tag;
        }
    }
}

__global__ void loss_kernel(const float* __restrict__ llh, float* __restrict__ out)
{
    float v = llh[threadIdx.x];
    #pragma unroll
    for (int off = 32; off > 0; off >>= 1) v += __shfl_down(v, off);
    if (threadIdx.x == 0) out[MM] = -(v / 64.f);
}

// ---------------------------------------------------------------------------
extern "C" void kernel_launch(void* const* d_in, const int* in_sizes, int n_in,
                              void* d_out, int out_size, void* d_ws, size_t ws_size,
                              hipStream_t stream)
{
    const int*   ids     = (const int*)  d_in[0];
    const int*   vlen    = (const int*)  d_in[1];
    const int*   labels  = (const int*)  d_in[2];
    const float* emb     = (const float*)d_in[3];
    const float* w_ih0   = (const float*)d_in[4];
    const float* w_hh0   = (const float*)d_in[5];
    const float* b_ih0   = (const float*)d_in[6];
    const float* b_hh0   = (const float*)d_in[7];
    const float* w_ih1   = (const float*)d_in[8];
    const float* w_hh1   = (const float*)d_in[9];
    const float* b_ih1   = (const float*)d_in[10];
    const float* b_hh1   = (const float*)d_in[11];
    const float* cls_w   = (const float*)d_in[12];
    const float* cls_b   = (const float*)d_in[13];
    const float* trans   = (const float*)d_in[14];
    const float* start_t = (const float*)d_in[15];
    const float* end_t   = (const float*)d_in[16];

    // Workspace (~125 MB):
    // [logits 1.18MB][llh][cnt 16u32][hbuf0 256KB][hbuf1 256KB][h0out 64MB]
    // [packA0 6MB][packA1 12MB][plog 37.7MB]
    float*          logits = (float*)d_ws;
    float*          llh    = logits + (size_t)MM * TT;
    unsigned*       cnt    = (unsigned*)(llh + 64);
    unsigned short* hbuf0  = (unsigned short*)(cnt + 16);
    unsigned short* hbuf1  = hbuf0 + 131072;
    unsigned short* h0out  = hbuf1 + 131072;
    unsigned short* packA0 = h0out + (size_t)MM * HD;
    unsigned short* packA1 = packA0 + 3145728;
    float*          plog   = (float*)(packA1 + 6291456);

    // zero: cnt(64B) + hbuf0 + hbuf1 (contiguous) = 131088 floats
    zero_kernel<<<512, 256, 0, stream>>>((float*)cnt, 16/4 + (131072 + 131072) / 2);

    pack_kernel<<<(3145728 + 255) / 256, 256, 0, stream>>>(w_ih0, w_hh0, packA0, EE, 12, 3145728);
    pack_kernel<<<(6291456 + 255) / 256, 256, 0, stream>>>(w_ih1, w_hh1, packA1, HD, 24, 6291456);

    bilstm_persist<0><<<32, 128, 0, stream>>>(
        ids, emb, nullptr, packA0, b_ih0, b_hh0, nullptr, hbuf0, h0out, nullptr, cnt);
    bilstm_persist<1><<<32, 128, 0, stream>>>(
        ids, nullptr, h0out, packA1, b_ih1, b_hh1, cls_w, hbuf1, nullptr, plog, cnt + 2);

    reduce_logits<<<(MM * TT + 255) / 256, 256, 0, stream>>>(plog, logits);
    crf_kernel<<<BB, 64, 0, stream>>>(logits, labels, vlen, trans, start_t, end_t,
                                      cls_b, (float*)d_out, llh);
    loss_kernel<<<1, 64, 0, stream>>>(llh, (float*)d_out);
}

// Round 5
// 40533.926 us; speedup vs baseline: 2.5674x; 1.0181x over previous
//
#include <hip/hip_runtime.h>
#include <math.h>

// Problem constants
#define BB 64
#define SS 512
#define EE 256
#define HH 512
#define HD 1024
#define TT 9
#define MM (BB*SS)

typedef __attribute__((ext_vector_type(8))) short      short8;   // 8 bf16
typedef __attribute__((ext_vector_type(4))) float      f32x4;
typedef __attribute__((ext_vector_type(4))) unsigned   uint4v;

__device__ __forceinline__ unsigned short f2bfu(float x) {
    unsigned b = __float_as_uint(x);
    b += 0x7FFFu + ((b >> 16) & 1u);      // RNE
    return (unsigned short)(b >> 16);
}
__device__ __forceinline__ unsigned pack2bf(float lo, float hi) {
    return ((unsigned)f2bfu(hi) << 16) | (unsigned)f2bfu(lo);
}

// ---------------------------------------------------------------------------
__global__ void zero_kernel(float* __restrict__ p, int n)
{
    int i = blockIdx.x * blockDim.x + threadIdx.x;
    int stride = gridDim.x * blockDim.x;
    for (; i < n; i += stride) p[i] = 0.f;
}

// ---------------------------------------------------------------------------
// Pack [w_ih | w_hh] (fp32) into MFMA-A-fragment-linear bf16:
// dst[tid], tid = ((((d*16+jb)*nch + ch)*16 + fr)*64 + lane)*8 + j
// fr = ksl*8 + mt; A-element: row r = mt*16 + (lane&15) -> gate q=r>>5, jj=r&31
// packed k = ch*64 + ksl*32 + (lane>>4)*8 + j;  k<KX -> w_ih else w_hh.
// ---------------------------------------------------------------------------
__global__ void pack_kernel(const float* __restrict__ w_ih, const float* __restrict__ w_hh,
                            unsigned short* __restrict__ dst, int KX, int nch, int total)
{
    int tid = blockIdx.x * 256 + threadIdx.x;
    if (tid >= total) return;
    int u = tid;
    int j    = u & 7;  u >>= 3;
    int lane = u & 63; u >>= 6;
    int fr   = u & 15; u >>= 4;
    int ch   = u % nch; u /= nch;
    int jb   = u & 15; u >>= 4;
    int d    = u;
    int ksl = fr >> 3, mt = fr & 7;
    int quad = lane >> 4, m = lane & 15;
    int r = mt * 16 + m;
    int q = r >> 5, jj = r & 31;
    int row = q * HH + jb * 32 + jj;
    int kp  = ch * 64 + ksl * 32 + quad * 8 + j;
    float v;
    if (kp < KX) v = w_ih[((size_t)d * 2048 + row) * (size_t)KX + kp];
    else         v = w_hh[((size_t)d * 2048 + row) * (size_t)HH + (kp - KX)];
    dst[tid] = f2bfu(v);
}

// ---------------------------------------------------------------------------
// Persistent BiLSTM layer. 32 blocks x 128 threads (2 waves), all resident.
//   bid>>4 = dir d, bid&15 = jb (32 hidden units). Wave wv owns batch tiles
//   {2wv, 2wv+1} (n-split). Gates via mfma_f32_16x16x32_bf16, fp32 accum.
// K-chunks (64 wide): [x: KX/64 chunks][h: 8 chunks]. x-chunks run BEFORE the
// 16-block per-dir barrier wait -> sync latency partly hidden. A double-
// buffered in frag-linear LDS (conflict-free b128). B prefetched 1 chunk
// ahead in regs.
//
// SYNC DESIGN (round-5 fix): h data moves via RELAXED agent-scope atomics
// (bypass L1/L2 to the MALL coherence point), so NO acquire/release cache
// maintenance is needed. Round 4 used ACQUIRE polls (buffer_inv per poll ->
// weights evicted from L2 every chunk -> 800 MB HBM refetch, 10x stall) and
// RELEASE adds (buffer_wbl2 per step). Now: consumer polls RELAXED; producer
// does RELAXED fetch_add AFTER __syncthreads(), whose compiler-emitted
// s_waitcnt vmcnt(0) drains the h stores to MALL before the add issues.
// ---------------------------------------------------------------------------
template<int LAYER>
__global__ __launch_bounds__(128, 1)
void bilstm_persist(const int* __restrict__ ids, const float* __restrict__ emb,
                    const unsigned short* __restrict__ x1,
                    const unsigned short* __restrict__ packA,
                    const float* __restrict__ b_ih, const float* __restrict__ b_hh,
                    const float* __restrict__ cls_w,
                    unsigned short* hbuf,                // [2 dir][2 ping][64][512] bf16
                    unsigned short* __restrict__ h0out,  // layer0 out (bf16)
                    float* __restrict__ plog,            // [32][64][512][9]
                    unsigned* cnt)
{
    constexpr int KX  = LAYER ? HD : EE;
    constexpr int NCH = (KX + HH) / 64;
    constexpr int XCH = KX / 64;

    __shared__ uint4v Abuf[2][1024];    // 2 x 16 KB, frag-linear

    const int bid  = blockIdx.x;
    const int d    = bid >> 4;
    const int jb   = bid & 15;
    const int tid  = threadIdx.x;
    const int lane = tid & 63;
    const int wv   = tid >> 6;
    const int quad = lane >> 4;
    const int ln15 = lane & 15;
    const int b0   = (wv * 2 + 0) * 16 + ln15;
    const int b1   = (wv * 2 + 1) * 16 + ln15;

    const unsigned short* myA = packA + (size_t)((d * 16 + jb) * NCH) * 8192;

    float bias_[4][2][4];
    #pragma unroll
    for (int q = 0; q < 4; q++)
        #pragma unroll
        for (int hi = 0; hi < 2; hi++)
            #pragma unroll
            for (int i = 0; i < 4; i++) {
                int jj  = hi * 16 + quad * 4 + i;
                int row = d * 2048 + q * HH + jb * 32 + jj;
                bias_[q][hi][i] = b_ih[row] + b_hh[row];
            }

    float clsw[8][TT];
    if (LAYER == 1) {
        #pragma unroll
        for (int hi = 0; hi < 2; hi++)
            #pragma unroll
            for (int i = 0; i < 4; i++) {
                int jj = hi * 16 + quad * 4 + i;
                #pragma unroll
                for (int n = 0; n < TT; n++)
                    clsw[hi * 4 + i][n] = cls_w[n * HD + d * HH + jb * 32 + jj];
            }
    }

    auto stageA = [&](int ch, int bb) {
        const uint4v* src = (const uint4v*)(myA + (size_t)ch * 8192);
        #pragma unroll
        for (int r = 0; r < 8; r++)
            Abuf[bb][tid + r * 128] = src[tid + r * 128];
    };

    // B-fragment: lane holds B[k=quad*8+j][n] = src[n][k0+quad*8+j] (8 bf16)
    auto loadB = [&](int ch, int t, int p, int ksl, int b) -> uint4v {
        int k0 = ch * 64 + ksl * 32 + quad * 8;
        uint4v u;
        if (ch < XCH) {
            if (LAYER == 0) {
                int id = ids[b * SS + t];
                const float* er = emb + (size_t)id * EE + k0;
                float4 f0 = *(const float4*)(er);
                float4 f1 = *(const float4*)(er + 4);
                u[0] = pack2bf(f0.x, f0.y);
                u[1] = pack2bf(f0.z, f0.w);
                u[2] = pack2bf(f1.x, f1.y);
                u[3] = pack2bf(f1.z, f1.w);
            } else {
                u = *(const uint4v*)(x1 + ((size_t)(b * SS + t)) * HD + k0);
            }
        } else {
            int kh = (ch - XCH) * 64 + ksl * 32 + quad * 8;
            const unsigned long long* hp = (const unsigned long long*)
                (hbuf + ((size_t)((d * 2 + p) * BB + b)) * HH + kh);
            unsigned long long l0 = __hip_atomic_load(hp,     __ATOMIC_RELAXED, __HIP_MEMORY_SCOPE_AGENT);
            unsigned long long l1 = __hip_atomic_load(hp + 1, __ATOMIC_RELAXED, __HIP_MEMORY_SCOPE_AGENT);
            u[0] = (unsigned)l0; u[1] = (unsigned)(l0 >> 32);
            u[2] = (unsigned)l1; u[3] = (unsigned)(l1 >> 32);
        }
        return u;
    };

    float  c_[2][2][4] = {};            // [nt-local][hi][i]
    f32x4  acc[8][2];
    uint4v breg[2][2][2];               // [buf][ksl][nt-local]

    // prime: stage chunk 0, prefetch its B (step 0)
    stageA(0, 0);
    {
        int t0 = d ? (SS - 1) : 0;
        #pragma unroll
        for (int ksl = 0; ksl < 2; ksl++) {
            breg[0][ksl][0] = loadB(0, t0, 0, ksl, b0);
            breg[0][ksl][1] = loadB(0, t0, 0, ksl, b1);
        }
    }

    for (int s = 0; s < SS; s++) {
        const int t   = d ? (SS - 1 - s) : s;
        const int tn  = d ? (t - 1) : (t + 1);
        const int tnc = tn < 0 ? 0 : (tn > SS - 1 ? SS - 1 : tn);
        const int p   = s & 1;

        #pragma unroll
        for (int mt = 0; mt < 8; mt++) {
            acc[mt][0] = f32x4{0.f, 0.f, 0.f, 0.f};
            acc[mt][1] = f32x4{0.f, 0.f, 0.f, 0.f};
        }

        for (int ch = 0; ch < NCH; ch++) {
            const int cur = ch & 1, nxt = cur ^ 1;
            __syncthreads();                      // Abuf[cur]/breg[cur] ready; Abuf[nxt] free
            if (ch == XCH - 1) {                  // before first h prefetch
                if (tid == 0) {
                    unsigned tgt = 16u * (unsigned)s;
                    // RELAXED poll: no cache invalidate (h data path is
                    // MALL-coherent atomics; nothing stale can be cached)
                    while (__hip_atomic_load(&cnt[d], __ATOMIC_RELAXED,
                                             __HIP_MEMORY_SCOPE_AGENT) < tgt)
                        __builtin_amdgcn_s_sleep(1);
                }
                __atomic_signal_fence(__ATOMIC_ACQ_REL);   // compiler-only fence
                __syncthreads();
            }
            // stage + prefetch next chunk (wraps to next step's chunk 0 = x)
            {
                int ch2 = ch + 1, t2 = t, p2 = p;
                if (ch2 == NCH) { ch2 = 0; t2 = tnc; p2 = p ^ 1; }
                stageA(ch2, nxt);
                #pragma unroll
                for (int ksl = 0; ksl < 2; ksl++) {
                    breg[nxt][ksl][0] = loadB(ch2, t2, p2, ksl, b0);
                    breg[nxt][ksl][1] = loadB(ch2, t2, p2, ksl, b1);
                }
            }
            // MFMA current chunk: 2 ksl x 8 mt x 2 nt
            #pragma unroll
            for (int ksl = 0; ksl < 2; ksl++) {
                short8 bf0 = __builtin_bit_cast(short8, breg[cur][ksl][0]);
                short8 bf1 = __builtin_bit_cast(short8, breg[cur][ksl][1]);
                #pragma unroll
                for (int mt = 0; mt < 8; mt++) {
                    short8 a = __builtin_bit_cast(short8, Abuf[cur][(ksl * 8 + mt) * 64 + lane]);
                    acc[mt][0] = __builtin_amdgcn_mfma_f32_16x16x32_bf16(a, bf0, acc[mt][0], 0, 0, 0);
                    acc[mt][1] = __builtin_amdgcn_mfma_f32_16x16x32_bf16(a, bf1, acc[mt][1], 0, 0, 0);
                }
            }
        }

        // ---- epilogue: lane owns (b in {b0,b1}) x (jj = hi*16+quad*4+i)
        float pl[2][TT];
        if (LAYER == 1) {
            #pragma unroll
            for (int ntl = 0; ntl < 2; ntl++)
                #pragma unroll
                for (int n = 0; n < TT; n++) pl[ntl][n] = 0.f;
        }
        #pragma unroll
        for (int ntl = 0; ntl < 2; ntl++) {
            const int b = ntl ? b1 : b0;
            #pragma unroll
            for (int hi = 0; hi < 2; hi++) {
                #pragma unroll
                for (int i = 0; i < 4; i++) {
                    float gi = acc[0 + hi][ntl][i] + bias_[0][hi][i];
                    float gf = acc[2 + hi][ntl][i] + bias_[1][hi][i];
                    float gg = acc[4 + hi][ntl][i] + bias_[2][hi][i];
                    float go = acc[6 + hi][ntl][i] + bias_[3][hi][i];
                    float i_ = 1.f / (1.f + __expf(-gi));
                    float f_ = 1.f / (1.f + __expf(-gf));
                    float xg = fminf(fmaxf(gg, -15.f), 15.f);
                    float e2 = __expf(2.f * xg);
                    float g_ = (e2 - 1.f) / (e2 + 1.f);
                    float o_ = 1.f / (1.f + __expf(-go));
                    float cc = f_ * c_[ntl][hi][i] + i_ * g_;
                    c_[ntl][hi][i] = cc;
                    float xc  = fminf(fmaxf(cc, -15.f), 15.f);
                    float e2c = __expf(2.f * xc);
                    float th  = (e2c - 1.f) / (e2c + 1.f);
                    float hn  = o_ * th;
                    int jj = hi * 16 + quad * 4 + i;
                    __hip_atomic_store(hbuf + ((size_t)((d * 2 + (p ^ 1)) * BB + b)) * HH
                                            + jb * 32 + jj,
                                       f2bfu(hn), __ATOMIC_RELAXED, __HIP_MEMORY_SCOPE_AGENT);
                    if (LAYER == 0) {
                        h0out[((size_t)(b * SS + t)) * HD + d * HH + jb * 32 + jj] = f2bfu(hn);
                    } else {
                        #pragma unroll
                        for (int n = 0; n < TT; n++) pl[ntl][n] += hn * clsw[hi * 4 + i][n];
                    }
                }
            }
        }
        if (LAYER == 1) {
            #pragma unroll
            for (int ntl = 0; ntl < 2; ntl++)
                #pragma unroll
                for (int n = 0; n < TT; n++) {
                    float v = pl[ntl][n];
                    v += __shfl_xor(v, 16);
                    v += __shfl_xor(v, 32);
                    pl[ntl][n] = v;
                }
            if (ln15 == lane) {                   // lanes 0..15 (quad 0)
                #pragma unroll
                for (int ntl = 0; ntl < 2; ntl++) {
                    int b = (wv * 2 + ntl) * 16 + lane;
                    float* dstp = plog + (((size_t)(d * 16 + jb) * BB + b) * SS + t) * TT;
                    #pragma unroll
                    for (int n = 0; n < TT; n++) dstp[n] = pl[ntl][n];
                }
            }
        }
        // arrive: __syncthreads() emits s_waitcnt vmcnt(0) before s_barrier,
        // draining the h atomic stores to the MALL; the RELAXED add after it
        // therefore publishes in order WITHOUT any L2 writeback (no wbl2).
        __syncthreads();
        __atomic_signal_fence(__ATOMIC_ACQ_REL);
        if (tid == 0)
            __hip_atomic_fetch_add(&cnt[d], 1u, __ATOMIC_RELAXED, __HIP_MEMORY_SCOPE_AGENT);
    }
}

// ---------------------------------------------------------------------------
// logits[i] = sum over 32 (dir,jb) partials  (cls_b added in CRF kernel)
// ---------------------------------------------------------------------------
__global__ void reduce_logits(const float* __restrict__ plog, float* __restrict__ out)
{
    int i = blockIdx.x * 256 + threadIdx.x;
    if (i >= MM * TT) return;
    float s = 0.f;
    #pragma unroll
    for (int g = 0; g < 32; g++) s += plog[(size_t)g * (MM * TT) + i];
    out[i] = s;
}

// ---------------------------------------------------------------------------
// CRF viterbi + loss (validated rounds 2-4). cls_b folded here.
// ---------------------------------------------------------------------------
__global__ __launch_bounds__(64)
void crf_kernel(const float* __restrict__ logits, const int* __restrict__ labels,
                const int* __restrict__ vlens, const float* __restrict__ trans,
                const float* __restrict__ start_t, const float* __restrict__ end_t,
                const float* __restrict__ cls_b,
                float* __restrict__ tags_out, float* __restrict__ llh)
{
    const int b = blockIdx.x;
    const int lane = threadIdx.x;
    const int len = vlens[b];
    const float* em = logits + (size_t)b * (SS * TT);
    const int*  lab = labels + (size_t)b * SS;
    __shared__ unsigned char hist[(SS - 1) * TT];

    float cb = (lane < TT) ? cls_b[lane] : 0.f;
    float tcol[TT];
    #pragma unroll
    for (int i = 0; i < TT; i++) tcol[i] = (lane < TT) ? trans[i * TT + lane] : 0.f;
    float score = (lane < TT) ? (start_t[lane] + em[lane] + cb) : 0.f;
    float alpha = score;
    float num = 0.f; int plab = 0;
    if (lane == 0) { plab = lab[0]; num = start_t[plab] + em[plab] + cls_b[plab]; }

    for (int t = 1; t < SS; t++) {
        float emj = (lane < TT) ? (em[t * TT + lane] + cb) : 0.f;
        float sv[TT], av[TT];
        #pragma unroll
        for (int i = 0; i < TT; i++) { sv[i] = __shfl(score, i); av[i] = __shfl(alpha, i); }
        float best = -INFINITY; int bp = 0; float amx = -INFINITY;
        #pragma unroll
        for (int i = 0; i < TT; i++) {
            float cnd = sv[i] + tcol[i];
            if (cnd > best) { best = cnd; bp = i; }   // strict >: FIRST max
            amx = fmaxf(amx, av[i] + tcol[i]);
        }
        float se = 0.f;
        #pragma unroll
        for (int i = 0; i < TT; i++) se += expf(av[i] + tcol[i] - amx);
        const bool m = (t < len);
        if (m) { score = best + emj; alpha = amx + logf(se) + emj; }
        if (lane < TT) hist[(t - 1) * TT + lane] = (unsigned char)bp;
        if (lane == 0 && m) {
            int lt = lab[t];
            num += em[t * TT + lt] + cls_b[lt] + trans[plab * TT + lt];
            plab = lt;
        }
    }
    float fsc[TT], fal[TT];
    #pragma unroll
    for (int i = 0; i < TT; i++) { fsc[i] = __shfl(score, i); fal[i] = __shfl(alpha, i); }
    __syncthreads();
    if (lane == 0) {
        num += end_t[lab[len - 1]];
        int bl = 0; float bv = fsc[0] + end_t[0];
        #pragma unroll
        for (int i = 1; i < TT; i++) {
            float v = fsc[i] + end_t[i];
            if (v > bv) { bv = v; bl = i; }
        }
        float zmx = -INFINITY;
        #pragma unroll
        for (int i = 0; i < TT; i++) zmx = fmaxf(zmx, fal[i] + end_t[i]);
        float zse = 0.f;
        #pragma unroll
        for (int i = 0; i < TT; i++) zse += expf(fal[i] + end_t[i] - zmx);
        llh[b] = num - (zmx + logf(zse));
        int tag = bl;
        tags_out[b * SS + (SS - 1)] = (float)tag;
        for (int t = SS - 2; t >= 0; t--) {
            if (t + 1 < len) tag = hist[t * TT + tag];
            tags_out[b * SS + t] = (float)tag;
        }
    }
}

__global__ void loss_kernel(const float* __restrict__ llh, float* __restrict__ out)
{
    float v = llh[threadIdx.x];
    #pragma unroll
    for (int off = 32; off > 0; off >>= 1) v += __shfl_down(v, off);
    if (threadIdx.x == 0) out[MM] = -(v / 64.f);
}

// ---------------------------------------------------------------------------
extern "C" void kernel_launch(void* const* d_in, const int* in_sizes, int n_in,
                              void* d_out, int out_size, void* d_ws, size_t ws_size,
                              hipStream_t stream)
{
    const int*   ids     = (const int*)  d_in[0];
    const int*   vlen    = (const int*)  d_in[1];
    const int*   labels  = (const int*)  d_in[2];
    const float* emb     = (const float*)d_in[3];
    const float* w_ih0   = (const float*)d_in[4];
    const float* w_hh0   = (const float*)d_in[5];
    const float* b_ih0   = (const float*)d_in[6];
    const float* b_hh0   = (const float*)d_in[7];
    const float* w_ih1   = (const float*)d_in[8];
    const float* w_hh1   = (const float*)d_in[9];
    const float* b_ih1   = (const float*)d_in[10];
    const float* b_hh1   = (const float*)d_in[11];
    const float* cls_w   = (const float*)d_in[12];
    const float* cls_b   = (const float*)d_in[13];
    const float* trans   = (const float*)d_in[14];
    const float* start_t = (const float*)d_in[15];
    const float* end_t   = (const float*)d_in[16];

    // Workspace (~125 MB):
    // [logits 1.18MB][llh][cnt 16u32][hbuf0 256KB][hbuf1 256KB][h0out 64MB]
    // [packA0 6MB][packA1 12MB][plog 37.7MB]
    float*          logits = (float*)d_ws;
    float*          llh    = logits + (size_t)MM * TT;
    unsigned*       cnt    = (unsigned*)(llh + 64);
    unsigned short* hbuf0  = (unsigned short*)(cnt + 16);
    unsigned short* hbuf1  = hbuf0 + 131072;
    unsigned short* h0out  = hbuf1 + 131072;
    unsigned short* packA0 = h0out + (size_t)MM * HD;
    unsigned short* packA1 = packA0 + 3145728;
    float*          plog   = (float*)(packA1 + 6291456);

    // zero: cnt(16B) + hbuf0 + hbuf1 (contiguous region after llh)
    zero_kernel<<<512, 256, 0, stream>>>((float*)cnt, 4 + (131072 + 131072) / 2);

    pack_kernel<<<(3145728 + 255) / 256, 256, 0, stream>>>(w_ih0, w_hh0, packA0, EE, 12, 3145728);
    pack_kernel<<<(6291456 + 255) / 256, 256, 0, stream>>>(w_ih1, w_hh1, packA1, HD, 24, 6291456);

    bilstm_persist<0><<<32, 128, 0, stream>>>(
        ids, emb, nullptr, packA0, b_ih0, b_hh0, nullptr, hbuf0, h0out, nullptr, cnt);
    bilstm_persist<1><<<32, 128, 0, stream>>>(
        ids, nullptr, h0out, packA1, b_ih1, b_hh1, cls_w, hbuf1, nullptr, plog, cnt + 2);

    reduce_logits<<<(MM * TT + 255) / 256, 256, 0, stream>>>(plog, logits);
    crf_kernel<<<BB, 64, 0, stream>>>(logits, labels, vlen, trans, start_t, end_t,
                                      cls_b, (float*)d_out, llh);
    loss_kernel<<<1, 64, 0, stream>>>(llh, (float*)d_out);
}